// Round 1
// baseline (802.045 us; speedup 1.0000x reference)
//
#include <hip/hip_runtime.h>
#include <hip/hip_bf16.h>
#include <stdint.h>

// Problem dims (JointNetwork): B=4, T=512, U=100, A_FEAT=512, TXT_FEAT=320, HID=640, NCLS=512
// Inputs/outputs are FLOAT32 (per reference). Internal compute: bf16 MFMA, f32 accumulate.
#define BB   4
#define TT   512
#define UU   100
#define AF   512
#define TXF  320
#define HID  640
#define NCLS 512
#define TU   (TT * UU)   // 51200
#define M3   (BB * TU)   // 204800

typedef unsigned short ushort_t;
typedef __attribute__((ext_vector_type(8))) short frag_ab;           // 8 bf16 = 4 VGPRs (MFMA A/B)
typedef __attribute__((ext_vector_type(4))) float frag_cd;           // 4 f32 accum
typedef __attribute__((ext_vector_type(8))) unsigned short ushort8;  // 16B pack

__device__ __forceinline__ float bf2f(unsigned short h) {
    return __uint_as_float(((unsigned)h) << 16);
}
__device__ __forceinline__ unsigned short f2bf(float f) {
    unsigned u = __float_as_uint(f);
    u += 0x7FFFu + ((u >> 16) & 1u);   // round-to-nearest-even
    return (unsigned short)(u >> 16);
}
// tanh(x) = 1 - 2/(exp2(2*log2e*x)+1); saturates correctly at +-inf. ~1e-5 accuracy, plenty for bf16 out.
__device__ __forceinline__ float tanh_fast(float x) {
    float e = __builtin_amdgcn_exp2f(x * 2.8853900817779268f);
    return 1.0f - 2.0f * __builtin_amdgcn_rcpf(e + 1.0f);
}

// ---------------- weight transpose+cast (f32 [K][N] -> bf16 [N][K]) ----------------
__global__ void tcast_kernel(const float* __restrict__ src, ushort_t* __restrict__ dst,
                             int K, int N) {
    int i = blockIdx.x * 256 + threadIdx.x;
    if (i >= K * N) return;
    int k = i / N;
    int n = i - k * N;
    dst[n * K + k] = f2bf(src[i]);
}

// ---------------- projection GEMM: P[M][HID] = X[M][K] @ W[K][HID] + bias, bf16 out ----------------
// X is f32; Wt is pre-transposed bf16 [HID][K]; bias f32; P bf16.
// 128x128 tile, 4 waves (2x2), 16x16x32 bf16 MFMA, BK=64.
__global__ __launch_bounds__(256) void proj_kernel(
    const float* __restrict__ X, const ushort_t* __restrict__ Wt,
    const float* __restrict__ bias, ushort_t* __restrict__ P,
    int M, int K)
{
    __shared__ ushort_t As[128][72];   // +8 pad; rows are 144B = 16B-aligned
    __shared__ ushort_t Bs[128][72];
    int tid = threadIdx.x;
    int m0 = blockIdx.x * 128, n0 = blockIdx.y * 128;
    int wave = tid >> 6, lane = tid & 63;
    int wr = (wave >> 1) * 64, wc = (wave & 1) * 64;
    int lm = lane & 15, lq = lane >> 4;
    frag_cd acc[4][4];
    #pragma unroll
    for (int i = 0; i < 4; ++i)
        #pragma unroll
        for (int j = 0; j < 4; ++j) { frag_cd z = {0.f, 0.f, 0.f, 0.f}; acc[i][j] = z; }
    int rs = tid >> 3, k8 = tid & 7;

    for (int k0 = 0; k0 < K; k0 += 64) {
        #pragma unroll
        for (int it = 0; it < 4; ++it) {
            int r = rs + it * 32;
            int m = m0 + r;
            float4 v0 = make_float4(0.f, 0.f, 0.f, 0.f), v1 = v0;
            if (m < M) {
                const float* xp = X + (size_t)m * K + (k0 + k8 * 8);
                v0 = *(const float4*)xp;
                v1 = *(const float4*)(xp + 4);
            }
            ushort8 o;
            o[0] = f2bf(v0.x); o[1] = f2bf(v0.y); o[2] = f2bf(v0.z); o[3] = f2bf(v0.w);
            o[4] = f2bf(v1.x); o[5] = f2bf(v1.y); o[6] = f2bf(v1.z); o[7] = f2bf(v1.w);
            *(ushort8*)&As[r][k8 * 8] = o;
            uint4 w = *(const uint4*)(Wt + (size_t)(n0 + r) * K + (k0 + k8 * 8));
            *(uint4*)&Bs[r][k8 * 8] = w;
        }
        __syncthreads();
        #pragma unroll
        for (int kk = 0; kk < 64; kk += 32) {
            frag_ab af[4], bfr[4];
            #pragma unroll
            for (int i = 0; i < 4; ++i) af[i]  = *(const frag_ab*)&As[wr + i * 16 + lm][kk + lq * 8];
            #pragma unroll
            for (int j = 0; j < 4; ++j) bfr[j] = *(const frag_ab*)&Bs[wc + j * 16 + lm][kk + lq * 8];
            #pragma unroll
            for (int i = 0; i < 4; ++i)
                #pragma unroll
                for (int j = 0; j < 4; ++j)
                    acc[i][j] = __builtin_amdgcn_mfma_f32_16x16x32_bf16(af[i], bfr[j], acc[i][j], 0, 0, 0);
        }
        __syncthreads();
    }
    // epilogue: C/D layout col=lane&15, row=(lane>>4)*4+reg (m89-verified)
    #pragma unroll
    for (int j = 0; j < 4; ++j) {
        int n = n0 + wc + j * 16 + lm;
        float bv = bias[n];
        #pragma unroll
        for (int i = 0; i < 4; ++i) {
            int mb = m0 + wr + i * 16 + lq * 4;
            #pragma unroll
            for (int r = 0; r < 4; ++r) {
                int m = mb + r;
                if (m < M) P[(size_t)m * HID + n] = f2bf(acc[i][j][r] + bv);
            }
        }
    }
}

// ---------------- fused joint: out[m][v] = tanh(a[b,ti,:] + t[b,ui,:]) @ Wj + bj ----------------
// Block = 128 rows x 512 cols (FULL NCLS -> A-tile tanh generated exactly once per output row).
// 512 threads = 8 waves as 2x4 grid; wave tile 64x128; acc[4][8] = 128 f32/lane.
// Register-prefetch pipeline: next K-tile's global loads are issued BEFORE the MFMA phase so
// their latency hides under MFMA (plain reg loads survive s_barrier; waitcnt lands at first use).
// LDS: As 128x72 + Bs 512x72 + offsets = ~93 KB -> 1 block/CU, 2 waves/SIMD (VGPR-capped anyway).
__global__ __launch_bounds__(512, 2) void joint_kernel(
    const ushort_t* __restrict__ Pa, const ushort_t* __restrict__ Pt,
    const ushort_t* __restrict__ Wtj, const float* __restrict__ bj,
    float* __restrict__ out)
{
    __shared__ ushort_t As[128][72];
    __shared__ ushort_t Bs[512][72];
    __shared__ int aOff[128];
    __shared__ int tOff[128];
    int tid = threadIdx.x;
    int m0 = blockIdx.x * 128;
    if (tid < 128) {
        int m  = m0 + tid;
        int b  = m / TU;
        int rb = m - b * TU;
        int ti = rb / UU;
        int ui = rb - ti * UU;
        aOff[tid] = (b * TT + ti) * HID;
        tOff[tid] = (b * UU + ui) * HID;
    }
    int wave = tid >> 6, lane = tid & 63;
    int wr = (wave >> 2) * 64;        // {0, 64}
    int wc = (wave & 3) * 128;        // {0, 128, 256, 384}
    int lm = lane & 15, lq = lane >> 4;
    frag_cd acc[4][8];
    #pragma unroll
    for (int i = 0; i < 4; ++i)
        #pragma unroll
        for (int j = 0; j < 8; ++j) { frag_cd z = {0.f, 0.f, 0.f, 0.f}; acc[i][j] = z; }
    int rs = tid >> 3, k8 = tid & 7;   // rs in [0,64), k8 in [0,8)
    __syncthreads();

    // per-thread row offsets (LDS -> regs once)
    const int aO0 = aOff[rs], aO1 = aOff[rs + 64];
    const int tO0 = tOff[rs], tO1 = tOff[rs + 64];
    const int kcol = k8 * 8;

    uint4 bv[8];         // B prefetch: Wtj rows rs, rs+64, ..., rs+448
    uint4 av[2], tv[2];  // A prefetch: Pa/Pt for rows rs, rs+64

    // ---- prefetch K-tile 0 ----
    #pragma unroll
    for (int it = 0; it < 8; ++it)
        bv[it] = *(const uint4*)(Wtj + (size_t)(rs + it * 64) * HID + kcol);
    av[0] = *(const uint4*)(Pa + aO0 + kcol);
    av[1] = *(const uint4*)(Pa + aO1 + kcol);
    tv[0] = *(const uint4*)(Pt + tO0 + kcol);
    tv[1] = *(const uint4*)(Pt + tO1 + kcol);

    for (int k0 = 0; k0 < HID; k0 += 64) {
        // ---- staging phase: tanh(a+t) -> As, raw B -> Bs (consumes prefetch regs) ----
        #pragma unroll
        for (int it = 0; it < 2; ++it) {
            const unsigned* au = (const unsigned*)&av[it];
            const unsigned* tu = (const unsigned*)&tv[it];
            ushort8 o;
            #pragma unroll
            for (int j = 0; j < 4; ++j) {
                unsigned ua = au[j], ut = tu[j];
                float s0 = __uint_as_float(ua << 16) + __uint_as_float(ut << 16);
                float s1 = __uint_as_float(ua & 0xFFFF0000u) + __uint_as_float(ut & 0xFFFF0000u);
                o[2 * j]     = f2bf(tanh_fast(s0));
                o[2 * j + 1] = f2bf(tanh_fast(s1));
            }
            *(ushort8*)&As[rs + it * 64][kcol] = o;
        }
        #pragma unroll
        for (int it = 0; it < 8; ++it)
            *(uint4*)&Bs[rs + it * 64][kcol] = bv[it];

        // ---- issue next K-tile's global loads (overlap with MFMA below) ----
        if (k0 + 64 < HID) {
            int kn = k0 + 64 + kcol;
            #pragma unroll
            for (int it = 0; it < 8; ++it)
                bv[it] = *(const uint4*)(Wtj + (size_t)(rs + it * 64) * HID + kn);
            av[0] = *(const uint4*)(Pa + aO0 + kn);
            av[1] = *(const uint4*)(Pa + aO1 + kn);
            tv[0] = *(const uint4*)(Pt + tO0 + kn);
            tv[1] = *(const uint4*)(Pt + tO1 + kn);
        }
        __syncthreads();

        // ---- MFMA phase ----
        #pragma unroll
        for (int kk = 0; kk < 64; kk += 32) {
            frag_ab af[4], bfr[8];
            #pragma unroll
            for (int i = 0; i < 4; ++i) af[i]  = *(const frag_ab*)&As[wr + i * 16 + lm][kk + lq * 8];
            #pragma unroll
            for (int j = 0; j < 8; ++j) bfr[j] = *(const frag_ab*)&Bs[wc + j * 16 + lm][kk + lq * 8];
            #pragma unroll
            for (int i = 0; i < 4; ++i)
                #pragma unroll
                for (int j = 0; j < 8; ++j)
                    acc[i][j] = __builtin_amdgcn_mfma_f32_16x16x32_bf16(af[i], bfr[j], acc[i][j], 0, 0, 0);
        }
        __syncthreads();
    }

    // ---- epilogue: add bj, f32 store. out flat index = m*NCLS + n. ----
    #pragma unroll
    for (int j = 0; j < 8; ++j) {
        int n = wc + j * 16 + lm;
        float bvv = bj[n];
        #pragma unroll
        for (int i = 0; i < 4; ++i) {
            size_t mb = (size_t)(m0 + wr + i * 16 + lq * 4);
            #pragma unroll
            for (int r = 0; r < 4; ++r) {
                out[(mb + r) * (size_t)NCLS + n] = acc[i][j][r] + bvv;
            }
        }
    }
}

extern "C" void kernel_launch(void* const* d_in, const int* in_sizes, int n_in,
                              void* d_out, int out_size, void* d_ws, size_t ws_size,
                              hipStream_t stream)
{
    const float* audio = (const float*)d_in[0];  // [4,512,512] f32
    const float* text  = (const float*)d_in[1];  // [4,100,320] f32
    const float* Wa    = (const float*)d_in[2];  // [512,640]
    const float* ba    = (const float*)d_in[3];  // [640]
    const float* Wt    = (const float*)d_in[4];  // [320,640]
    const float* bt    = (const float*)d_in[5];  // [640]
    const float* Wj    = (const float*)d_in[6];  // [640,512]
    const float* bjv   = (const float*)d_in[7];  // [512]
    float* out = (float*)d_out;

    char* ws = (char*)d_ws;
    // ws layout (bytes, all bf16): Pa 2621440 | Pt 512000 | Wta 655360 | Wtt 409600 | Wtj 655360
    ushort_t* Pa  = (ushort_t*)(ws);
    ushort_t* Pt  = (ushort_t*)(ws + 2621440);
    ushort_t* Wta = (ushort_t*)(ws + 3133440);
    ushort_t* Wtt = (ushort_t*)(ws + 3788800);
    ushort_t* Wtj = (ushort_t*)(ws + 4198400);

    // weight transposes+casts: W[K][N] f32 -> Wt[N][K] bf16
    tcast_kernel<<<dim3((AF * HID + 255) / 256), 256, 0, stream>>>(Wa, Wta, AF, HID);
    tcast_kernel<<<dim3((TXF * HID + 255) / 256), 256, 0, stream>>>(Wt, Wtt, TXF, HID);
    tcast_kernel<<<dim3((HID * NCLS + 255) / 256), 256, 0, stream>>>(Wj, Wtj, HID, NCLS);

    // projections: a = audio@Wa + ba (M=2048, K=512), t = text@Wt + bt (M=400, K=320)
    proj_kernel<<<dim3(16, 5), 256, 0, stream>>>(audio, Wta, ba, Pa, BB * TT, AF);
    proj_kernel<<<dim3(4, 5), 256, 0, stream>>>(text, Wtt, bt, Pt, BB * UU, TXF);

    // fused tanh + final GEMM: [204800 x 640] @ [640 x 512] -> f32 out
    // One column-block (BN = NCLS = 512): tanh A-tile computed exactly once per output row.
    joint_kernel<<<dim3(M3 / 128), 512, 0, stream>>>(Pa, Pt, Wtj, bjv, out);
}

// Round 2
// 675.279 us; speedup vs baseline: 1.1877x; 1.1877x over previous
//
#include <hip/hip_runtime.h>
#include <hip/hip_bf16.h>
#include <stdint.h>

// Problem dims (JointNetwork): B=4, T=512, U=100, A_FEAT=512, TXT_FEAT=320, HID=640, NCLS=512
#define BB   4
#define TT   512
#define UU   100
#define AF   512
#define TXF  320
#define HID  640
#define NCLS 512
#define TU   (TT * UU)   // 51200
#define M3   (BB * TU)   // 204800
#define KT   (HID / 64)  // 10 K-tiles in the joint GEMM

typedef unsigned short ushort_t;
typedef __attribute__((ext_vector_type(8))) short frag_ab;           // 8 bf16 = 4 VGPRs (MFMA A/B)
typedef __attribute__((ext_vector_type(4))) float frag_cd;           // 4 f32 accum
typedef __attribute__((ext_vector_type(8))) unsigned short ushort8;  // 16B pack

__device__ __forceinline__ float bf2f(unsigned short h) {
    return __uint_as_float(((unsigned)h) << 16);
}
__device__ __forceinline__ unsigned short f2bf(float f) {
    unsigned u = __float_as_uint(f);
    u += 0x7FFFu + ((u >> 16) & 1u);   // round-to-nearest-even
    return (unsigned short)(u >> 16);
}
// tanh(x) = 1 - 2/(exp2(2*log2e*x)+1); saturates correctly at +-inf.
__device__ __forceinline__ float tanh_fast(float x) {
    float e = __builtin_amdgcn_exp2f(x * 2.8853900817779268f);
    return 1.0f - 2.0f * __builtin_amdgcn_rcpf(e + 1.0f);
}
// async global->LDS 16B copy; LDS dest must be wave-uniform base + lane*16 (ours is lane-linear).
__device__ __forceinline__ void gload_lds16(const ushort_t* g, ushort_t* l) {
    __builtin_amdgcn_global_load_lds(
        (const __attribute__((address_space(1))) unsigned int*)(const void*)g,
        (__attribute__((address_space(3))) unsigned int*)(void*)l,
        16, 0, 0);
}

// ---------------- weight transpose+cast (f32 [K][N] -> bf16 [N][K]) ----------------
__global__ void tcast_kernel(const float* __restrict__ src, ushort_t* __restrict__ dst,
                             int K, int N) {
    int i = blockIdx.x * 256 + threadIdx.x;
    if (i >= K * N) return;
    int k = i / N;
    int n = i - k * N;
    dst[n * K + k] = f2bf(src[i]);
}

// ---------------- Wj reorder: f32 [HID][NCLS] -> bf16 fragment-major ----------------
// Cell index idx = (k0t*64 + p*2 + q)*64 + lane, cell = 8 ushorts.
// Cell content d=0..7:  Wj[(k0t*64 + q*32 + (lane>>4)*8 + d)][p*16 + (lane&15)]
// so that in the joint kernel the B-fragment for (n-block p, k-half q) is a lane-linear
// ds_read_b128 at ((p*2+q)*64 + lane)*16B  — conflict-free, and stage-able with
// global_load_lds (linear dest).
__global__ void reorder_wj(const float* __restrict__ Wj, ushort_t* __restrict__ Wf) {
    int idx = blockIdx.x * 256 + threadIdx.x;   // 0 .. KT*64*64-1 = 40959
    if (idx >= KT * 64 * 64) return;
    int lane = idx & 63;
    int s    = (idx >> 6) & 63;   // p*2 + q
    int k0t  = idx >> 12;
    int q = s & 1, p = s >> 1;
    int n = p * 16 + (lane & 15);
    int k = k0t * 64 + q * 32 + (lane >> 4) * 8;
    ushort8 o;
    #pragma unroll
    for (int d = 0; d < 8; ++d) o[d] = f2bf(Wj[(size_t)(k + d) * NCLS + n]);
    *(ushort8*)&Wf[(size_t)idx * 8] = o;
}

// ---------------- projection GEMM (unchanged, small cost) ----------------
__global__ __launch_bounds__(256) void proj_kernel(
    const float* __restrict__ X, const ushort_t* __restrict__ Wt,
    const float* __restrict__ bias, ushort_t* __restrict__ P,
    int M, int K)
{
    __shared__ ushort_t As[128][72];
    __shared__ ushort_t Bs[128][72];
    int tid = threadIdx.x;
    int m0 = blockIdx.x * 128, n0 = blockIdx.y * 128;
    int wave = tid >> 6, lane = tid & 63;
    int wr = (wave >> 1) * 64, wc = (wave & 1) * 64;
    int lm = lane & 15, lq = lane >> 4;
    frag_cd acc[4][4];
    #pragma unroll
    for (int i = 0; i < 4; ++i)
        #pragma unroll
        for (int j = 0; j < 4; ++j) { frag_cd z = {0.f, 0.f, 0.f, 0.f}; acc[i][j] = z; }
    int rs = tid >> 3, k8 = tid & 7;

    for (int k0 = 0; k0 < K; k0 += 64) {
        #pragma unroll
        for (int it = 0; it < 4; ++it) {
            int r = rs + it * 32;
            int m = m0 + r;
            float4 v0 = make_float4(0.f, 0.f, 0.f, 0.f), v1 = v0;
            if (m < M) {
                const float* xp = X + (size_t)m * K + (k0 + k8 * 8);
                v0 = *(const float4*)xp;
                v1 = *(const float4*)(xp + 4);
            }
            ushort8 o;
            o[0] = f2bf(v0.x); o[1] = f2bf(v0.y); o[2] = f2bf(v0.z); o[3] = f2bf(v0.w);
            o[4] = f2bf(v1.x); o[5] = f2bf(v1.y); o[6] = f2bf(v1.z); o[7] = f2bf(v1.w);
            *(ushort8*)&As[r][k8 * 8] = o;
            uint4 w = *(const uint4*)(Wt + (size_t)(n0 + r) * K + (k0 + k8 * 8));
            *(uint4*)&Bs[r][k8 * 8] = w;
        }
        __syncthreads();
        #pragma unroll
        for (int kk = 0; kk < 64; kk += 32) {
            frag_ab af[4], bfr[4];
            #pragma unroll
            for (int i = 0; i < 4; ++i) af[i]  = *(const frag_ab*)&As[wr + i * 16 + lm][kk + lq * 8];
            #pragma unroll
            for (int j = 0; j < 4; ++j) bfr[j] = *(const frag_ab*)&Bs[wc + j * 16 + lm][kk + lq * 8];
            #pragma unroll
            for (int i = 0; i < 4; ++i)
                #pragma unroll
                for (int j = 0; j < 4; ++j)
                    acc[i][j] = __builtin_amdgcn_mfma_f32_16x16x32_bf16(af[i], bfr[j], acc[i][j], 0, 0, 0);
        }
        __syncthreads();
    }
    #pragma unroll
    for (int j = 0; j < 4; ++j) {
        int n = n0 + wc + j * 16 + lm;
        float bv = bias[n];
        #pragma unroll
        for (int i = 0; i < 4; ++i) {
            int mb = m0 + wr + i * 16 + lq * 4;
            #pragma unroll
            for (int r = 0; r < 4; ++r) {
                int m = mb + r;
                if (m < M) P[(size_t)m * HID + n] = f2bf(acc[i][j][r] + bv);
            }
        }
    }
}

// ---------------- fused joint: out[m][v] = tanh(a + t) @ Wj + bj ----------------
// Block 128 rows x 512 cols (full NCLS), 512 threads = 8 waves (2x4), wave tile 64x128.
// FRAGMENT-MAJOR LDS: every ds_read/ds_write is base + lane*16B (no bank conflicts).
//   As: 1024 cells; cell (i,q,lane) at ((i*2+q)*64+lane)*16B holds
//       tanh-A[row = i*16 + (lane&15)][k0 + q*32 + (lane>>4)*8 .. +8]
//   Bs: 4096 cells, same scheme over 32 n-blocks; staged linearly via global_load_lds
//       from the pre-reordered Wf (zero staging VGPRs, conflict-free writes).
// Pa/Pt tile t+1 prefetched into registers (double-set, static indices via full unroll).
// LDS = 16KB + 64KB = 80KB.
__global__ __launch_bounds__(512, 2) void joint_kernel(
    const ushort_t* __restrict__ Pa, const ushort_t* __restrict__ Pt,
    const ushort_t* __restrict__ Wf, const float* __restrict__ bj,
    float* __restrict__ out)
{
    __shared__ ushort_t As[1024 * 8];   // 16 KB
    __shared__ ushort_t Bs[4096 * 8];   // 64 KB
    const int tid  = threadIdx.x;
    const int m0   = blockIdx.x * 128;
    const int lane = tid & 63;
    const int wave = tid >> 6;
    const int lm = lane & 15, lq = lane >> 4;
    const int wr = (wave >> 2) * 64;      // {0,64}
    const int wc = (wave & 3) * 128;      // {0,128,256,384}
    const int iab = (wave >> 2) * 4;      // A fragment row-block base
    const int pb  = (wave & 3) * 8;       // B fragment n-block base

    // staging map: thread owns A-cells G = tid (it=0) and G = 512 + tid (it=1)
    //   row(it) = (tid>>7)*16 + (tid&15) + it*64 ; col = ((tid>>6)&1)*32 + ((tid>>4)&3)*8
    const int r0 = ((tid >> 7) << 4) | (tid & 15);
    const int c0 = (((tid >> 6) & 1) << 5) | (((tid >> 4) & 3) << 3);
    int aO0, aO1, tO0, tO1;
    {
        int m = m0 + r0;
        int b = m / TU; int rb = m - b * TU;
        int ti = rb / UU; int ui = rb - ti * UU;
        aO0 = (b * TT + ti) * HID; tO0 = (b * UU + ui) * HID;
        m += 64;
        b = m / TU; rb = m - b * TU;
        ti = rb / UU; ui = rb - ti * UU;
        aO1 = (b * TT + ti) * HID; tO1 = (b * UU + ui) * HID;
    }

    frag_cd acc[4][8];
    #pragma unroll
    for (int i = 0; i < 4; ++i)
        #pragma unroll
        for (int j = 0; j < 8; ++j) { frag_cd z = {0.f, 0.f, 0.f, 0.f}; acc[i][j] = z; }

    // Pa/Pt register prefetch, double-set; indices static after full unroll
    uint4 pav[2][2], ptv[2][2];
    pav[0][0] = *(const uint4*)(Pa + aO0 + c0);
    pav[0][1] = *(const uint4*)(Pa + aO1 + c0);
    ptv[0][0] = *(const uint4*)(Pt + tO0 + c0);
    ptv[0][1] = *(const uint4*)(Pt + tO1 + c0);

    #pragma unroll
    for (int t = 0; t < KT; ++t) {
        const int cur = t & 1, nxt = cur ^ 1;
        // stage B tile t (async, lane-linear LDS dest)
        #pragma unroll
        for (int c = 0; c < 8; ++c)
            gload_lds16(Wf + (size_t)(t * 4096 + c * 512 + tid) * 8,
                        &Bs[(c * 512 + tid) * 8]);
        // prefetch P tile t+1 into the other register set
        if (t + 1 < KT) {
            const int kn = (t + 1) * 64 + c0;
            pav[nxt][0] = *(const uint4*)(Pa + aO0 + kn);
            pav[nxt][1] = *(const uint4*)(Pa + aO1 + kn);
            ptv[nxt][0] = *(const uint4*)(Pt + tO0 + kn);
            ptv[nxt][1] = *(const uint4*)(Pt + tO1 + kn);
        }
        // tanh(a+t) -> As (lane-linear ds_write_b128)
        #pragma unroll
        for (int it = 0; it < 2; ++it) {
            const unsigned* au = (const unsigned*)&pav[cur][it];
            const unsigned* tu = (const unsigned*)&ptv[cur][it];
            ushort8 o;
            #pragma unroll
            for (int j = 0; j < 4; ++j) {
                unsigned ua = au[j], ut = tu[j];
                float s0 = __uint_as_float(ua << 16) + __uint_as_float(ut << 16);
                float s1 = __uint_as_float(ua & 0xFFFF0000u) + __uint_as_float(ut & 0xFFFF0000u);
                o[2 * j]     = f2bf(tanh_fast(s0));
                o[2 * j + 1] = f2bf(tanh_fast(s1));
            }
            *(ushort8*)&As[(it * 512 + tid) * 8] = o;
        }
        __syncthreads();   // drains gll + ds_writes; As/Bs tile t ready for all waves
        // MFMA phase: all frag reads are base + lane*16 (conflict-free)
        #pragma unroll
        for (int q = 0; q < 2; ++q) {
            frag_ab af[4], bfr[8];
            #pragma unroll
            for (int i = 0; i < 4; ++i)
                af[i] = *(const frag_ab*)&As[(((iab + i) * 2 + q) * 64 + lane) * 8];
            #pragma unroll
            for (int j = 0; j < 8; ++j)
                bfr[j] = *(const frag_ab*)&Bs[(((pb + j) * 2 + q) * 64 + lane) * 8];
            #pragma unroll
            for (int i = 0; i < 4; ++i)
                #pragma unroll
                for (int j = 0; j < 8; ++j)
                    acc[i][j] = __builtin_amdgcn_mfma_f32_16x16x32_bf16(af[i], bfr[j], acc[i][j], 0, 0, 0);
        }
        __syncthreads();   // protect As/Bs before next tile's staging
    }

    // epilogue: add bj, f32 store
    #pragma unroll
    for (int j = 0; j < 8; ++j) {
        int n = wc + j * 16 + lm;
        float bvv = bj[n];
        #pragma unroll
        for (int i = 0; i < 4; ++i) {
            size_t mb = (size_t)(m0 + wr + i * 16 + lq * 4);
            #pragma unroll
            for (int r = 0; r < 4; ++r) {
                out[(mb + r) * (size_t)NCLS + n] = acc[i][j][r] + bvv;
            }
        }
    }
}

extern "C" void kernel_launch(void* const* d_in, const int* in_sizes, int n_in,
                              void* d_out, int out_size, void* d_ws, size_t ws_size,
                              hipStream_t stream)
{
    const float* audio = (const float*)d_in[0];  // [4,512,512] f32
    const float* text  = (const float*)d_in[1];  // [4,100,320] f32
    const float* Wa    = (const float*)d_in[2];  // [512,640]
    const float* ba    = (const float*)d_in[3];  // [640]
    const float* Wt    = (const float*)d_in[4];  // [320,640]
    const float* bt    = (const float*)d_in[5];  // [640]
    const float* Wj    = (const float*)d_in[6];  // [640,512]
    const float* bjv   = (const float*)d_in[7];  // [512]
    float* out = (float*)d_out;

    char* ws = (char*)d_ws;
    // ws layout (bytes, all bf16): Pa 2621440 | Pt 512000 | Wta 655360 | Wtt 409600 | Wf 655360
    ushort_t* Pa  = (ushort_t*)(ws);
    ushort_t* Pt  = (ushort_t*)(ws + 2621440);
    ushort_t* Wta = (ushort_t*)(ws + 3133440);
    ushort_t* Wtt = (ushort_t*)(ws + 3788800);
    ushort_t* Wf  = (ushort_t*)(ws + 4198400);

    // weight prep
    tcast_kernel<<<dim3((AF * HID + 255) / 256), 256, 0, stream>>>(Wa, Wta, AF, HID);
    tcast_kernel<<<dim3((TXF * HID + 255) / 256), 256, 0, stream>>>(Wt, Wtt, TXF, HID);
    reorder_wj<<<dim3((KT * 64 * 64 + 255) / 256), 256, 0, stream>>>(Wj, Wf);

    // projections: a = audio@Wa + ba (M=2048, K=512), t = text@Wt + bt (M=400, K=320)
    proj_kernel<<<dim3(16, 5), 256, 0, stream>>>(audio, Wta, ba, Pa, BB * TT, AF);
    proj_kernel<<<dim3(4, 5), 256, 0, stream>>>(text, Wtt, bt, Pt, BB * UU, TXF);

    // fused tanh + final GEMM: [204800 x 640] @ [640 x 512] -> f32 out
    joint_kernel<<<dim3(M3 / 128), 512, 0, stream>>>(Pa, Pt, Wf, bjv, out);
}